// Round 1
// baseline (3849.097 us; speedup 1.0000x reference)
//
#include <hip/hip_runtime.h>
#include <math.h>

#define NBATCH 16384
#define NT 32
#define ND 64
#define NSLOT 16

typedef __attribute__((ext_vector_type(8))) __bf16 bf16x8;
typedef __attribute__((ext_vector_type(4))) float  f32x4;

// Output layout (flat fp32):
//   reads  [T][B][128] : 0          .. 67108863
//   mem_f  [B][16][128]: 67108864   .. 100663295
//   ptr_f  [B][16]     : 100663296  .. 100925439
//   active [1]         : 100925440
__global__ __launch_bounds__(256, 2)
void crsn_fused(const float* __restrict__ zre, const float* __restrict__ zim,
                const float* __restrict__ ctl, const float* __restrict__ mem0,
                const float* __restrict__ ptr0,
                const float* __restrict__ Wqr, const float* __restrict__ Wqi,
                const float* __restrict__ Wkr, const float* __restrict__ Wki,
                const float* __restrict__ Wvr, const float* __restrict__ Wvi,
                float* __restrict__ out)
{
    __shared__ __align__(16) float  zf[NT * 128];      // rope'd z_flat per step
    __shared__ __align__(16) __bf16 memb[16 * 136];    // bf16 mem (A operand), pad 8
    __shared__ __align__(16) __bf16 qfb[16 * 136];
    __shared__ __align__(16) __bf16 kfb[16 * 136];
    __shared__ __align__(16) float  vff[16 * 132];     // fp32 vf, pad 4
    __shared__ float4 pps[NT];                          // push,pop,stay per t
    __shared__ float  ptrA[16];
    __shared__ float  wbuf[16];

    const int tid  = threadIdx.x;
    const int b    = blockIdx.x;
    const int lane = tid & 63;
    const int wv   = tid >> 6;     // wave 0..3
    const int ln   = lane & 15;
    const int quad = lane >> 4;

    // ---- prefetch: rope'd z into LDS (trig computed inline, fp32) ----
    {
        const size_t zb = (size_t)b * (NT * ND);
        for (int idx = tid; idx < NT * ND; idx += 256) {
            int t = idx >> 6, d = idx & 63;
            float zr = zre[zb + idx];
            float zi = zim[zb + idx];
            // freq = 10000^{-(d%32)/32} ; ang = t * freq
            float fr  = expf(-0.28782313662425575f * (float)(d & 31));
            float ang = fr * (float)t;
            float sn, cs;
            sincosf(ang, &sn, &cs);
            zf[t * 128 + d]      = zr * cs - zi * sn;
            zf[t * 128 + 64 + d] = zr * sn + zi * cs;
        }
    }
    // gates per step
    if (tid < NT) {
        const float* c = ctl + ((size_t)b * NT + tid) * 3;
        float g0 = 1.f / (1.f + expf(-c[0]));
        float g1 = 1.f / (1.f + expf(-c[1]));
        float g2 = 1.f / (1.f + expf(-c[2]));
        float tot = g0 + g1 + g2 + 1e-6f;
        pps[tid] = make_float4(g0 / tot, g1 / tot, g2 / tot, 0.f);
    }
    if (tid < 16) ptrA[tid] = ptr0[(size_t)b * 16 + tid];

    // ---- fp32 mem master in registers: thread owns mem[ms][md0..md0+7] ----
    const int ms  = tid >> 4;
    const int md0 = (tid & 15) * 8;
    float m[8];
    {
        const float4* p = (const float4*)(mem0 + (size_t)b * 2048 + ms * 128 + md0);
        float4 a = p[0], c2 = p[1];
        m[0]=a.x;  m[1]=a.y;  m[2]=a.z;  m[3]=a.w;
        m[4]=c2.x; m[5]=c2.y; m[6]=c2.z; m[7]=c2.w;
    }

    // ---- B fragments (weights) in registers, reused for all 32 steps ----
    // Columns c in [0,384): [qr qi kr ki vr vi] x 64.  B[k][c]:
    //   real-out col: k<64 -> +W_r[e][k] ; k>=64 -> -W_i[e][k-64]
    //   imag-out col: k<64 -> +W_i[e][k] ; k>=64 -> +W_r[e][k-64]
    // b-frag lane: n = lane&15 (col within tile), k = kt*32 + quad*8 + j
    bf16x8 bfr[6][4];
    {
        #pragma unroll
        for (int i = 0; i < 6; ++i) {
            int nt   = wv * 6 + i;             // global n-tile 0..23
            int mat  = nt >> 3;                // 0:q 1:k 2:v
            int part = (nt >> 2) & 1;          // 0 real-out, 1 imag-out
            int e    = ((nt & 3) << 4) + ln;   // weight row
            const float* Wr = (mat == 0) ? Wqr : (mat == 1) ? Wkr : Wvr;
            const float* Wi = (mat == 0) ? Wqi : (mat == 1) ? Wki : Wvi;
            #pragma unroll
            for (int kt = 0; kt < 4; ++kt) {
                int k0   = kt * 32 + quad * 8;     // 8-run stays inside one half
                int half = k0 >> 6;
                int d0   = k0 & 63;
                const float* src = part ? (half ? Wr : Wi) : (half ? Wi : Wr);
                float sgn = (!part && half) ? -1.f : 1.f;
                const float4* p4 = (const float4*)(src + e * 64 + d0);
                float4 x = p4[0], y = p4[1];
                bf16x8 f;
                f[0]=(__bf16)(sgn*x.x); f[1]=(__bf16)(sgn*x.y);
                f[2]=(__bf16)(sgn*x.z); f[3]=(__bf16)(sgn*x.w);
                f[4]=(__bf16)(sgn*y.x); f[5]=(__bf16)(sgn*y.y);
                f[6]=(__bf16)(sgn*y.z); f[7]=(__bf16)(sgn*y.w);
                bfr[i][kt] = f;
            }
        }
    }

    __syncthreads();

    const size_t rbase = (size_t)b * 128;

    for (int t = 0; t < NT; ++t) {
        // (1) mem update (fp32 regs) + bf16 shadow into LDS
        {
            float4 g = pps[t];
            float p = g.x, om = 1.f - g.x;
            const float4* z4 = (const float4*)&zf[t * 128 + md0];
            float4 za = z4[0], zc = z4[1];
            m[0]=m[0]*om + p*za.x; m[1]=m[1]*om + p*za.y;
            m[2]=m[2]*om + p*za.z; m[3]=m[3]*om + p*za.w;
            m[4]=m[4]*om + p*zc.x; m[5]=m[5]*om + p*zc.y;
            m[6]=m[6]*om + p*zc.z; m[7]=m[7]*om + p*zc.w;
            bf16x8 mb;
            mb[0]=(__bf16)m[0]; mb[1]=(__bf16)m[1]; mb[2]=(__bf16)m[2]; mb[3]=(__bf16)m[3];
            mb[4]=(__bf16)m[4]; mb[5]=(__bf16)m[5]; mb[6]=(__bf16)m[6]; mb[7]=(__bf16)m[7];
            *(bf16x8*)&memb[ms * 136 + md0] = mb;
        }
        __syncthreads();

        // (3) ptr recurrence (wave0 lanes<16, wave-lockstep read-then-write) + QKV MFMA (all waves)
        if (wv == 0 && lane < 16) {
            float4 g = pps[t];
            float pm = ptrA[(lane + 15) & 15];
            float pp = ptrA[(lane + 1) & 15];
            float pc = ptrA[lane];
            float np = g.x * pm + g.y * pp + g.z * pc;
            ptrA[lane] = np;
        }
        {
            bf16x8 af[4];
            #pragma unroll
            for (int kt = 0; kt < 4; ++kt)
                af[kt] = *(const bf16x8*)&memb[ln * 136 + kt * 32 + quad * 8];
            f32x4 acc[6] = {};
            #pragma unroll
            for (int i = 0; i < 6; ++i) {
                #pragma unroll
                for (int kt = 0; kt < 4; ++kt)
                    acc[i] = __builtin_amdgcn_mfma_f32_16x16x32_bf16(af[kt], bfr[i][kt], acc[i], 0, 0, 0);
            }
            // D: col = lane&15 (+16*nt), row = quad*4 + reg
            #pragma unroll
            for (int i = 0; i < 6; ++i) {
                int nt = wv * 6 + i;
                int c  = nt * 16 + ln;
                #pragma unroll
                for (int r = 0; r < 4; ++r) {
                    int row = quad * 4 + r;
                    float v = acc[i][r];
                    if (c < 128)      qfb[row * 136 + c]          = (__bf16)v;
                    else if (c < 256) kfb[row * 136 + (c - 128)]  = (__bf16)v;
                    else              vff[row * 132 + (c - 256)]  = v;
                }
            }
        }
        __syncthreads();

        // (5) scores + softmax + w[u] (wave 0 only)
        if (wv == 0) {
            bf16x8 qa[4], ka[4];
            #pragma unroll
            for (int kt = 0; kt < 4; ++kt) {
                qa[kt] = *(const bf16x8*)&qfb[ln * 136 + kt * 32 + quad * 8];
                ka[kt] = *(const bf16x8*)&kfb[ln * 136 + kt * 32 + quad * 8];
            }
            f32x4 sc = {};
            #pragma unroll
            for (int kt = 0; kt < 4; ++kt)
                sc = __builtin_amdgcn_mfma_f32_16x16x32_bf16(qa[kt], ka[kt], sc, 0, 0, 0);
            // sc[r] = S[row=quad*4+r][u=ln]; softmax over u (16 lanes within quad)
            float wpart = 0.f;
            #pragma unroll
            for (int r = 0; r < 4; ++r) {
                float v  = sc[r] * 0.125f;
                float mx = v;
                mx = fmaxf(mx, __shfl_xor(mx, 1));
                mx = fmaxf(mx, __shfl_xor(mx, 2));
                mx = fmaxf(mx, __shfl_xor(mx, 4));
                mx = fmaxf(mx, __shfl_xor(mx, 8));
                float ex = expf(v - mx);
                float sm = ex;
                sm += __shfl_xor(sm, 1);
                sm += __shfl_xor(sm, 2);
                sm += __shfl_xor(sm, 4);
                sm += __shfl_xor(sm, 8);
                float pr = ex / sm;                 // attn[row][u]
                wpart += ptrA[quad * 4 + r] * pr;   // new_ptr[row]*attn
            }
            wpart += __shfl_xor(wpart, 16);
            wpart += __shfl_xor(wpart, 32);
            if (lane < 16) wbuf[lane] = wpart;      // w[u]
        }
        __syncthreads();

        // (7) read[e] = sum_u w[u]*vf[u][e] -> global
        if (tid < 128) {
            float acc = 0.f;
            #pragma unroll
            for (int u = 0; u < 16; ++u)
                acc += wbuf[u] * vff[u * 132 + tid];
            out[(size_t)t * (NBATCH * 128) + rbase + tid] = acc;
        }
        __syncthreads();
    }

    // ---- finals ----
    {
        float* mo = out + 67108864ULL + (size_t)b * 2048 + ms * 128 + md0;
        float4 a = {m[0], m[1], m[2], m[3]};
        float4 c2 = {m[4], m[5], m[6], m[7]};
        ((float4*)mo)[0] = a;
        ((float4*)mo)[1] = c2;
    }
    if (tid < 16) out[100663296ULL + (size_t)b * 16 + tid] = ptrA[tid];
    if (tid < 64) {
        float pv = ptrA[tid & 15];
        unsigned long long mk = __ballot((tid < 16) && (pv > 0.1f));
        if (tid == 0)
            atomicAdd(out + 100925440ULL, (float)__popcll(mk) * (1.0f / 16384.f));
    }
}

extern "C" void kernel_launch(void* const* d_in, const int* in_sizes, int n_in,
                              void* d_out, int out_size, void* d_ws, size_t ws_size,
                              hipStream_t stream) {
    (void)in_sizes; (void)n_in; (void)d_ws; (void)ws_size;
    const float* zre  = (const float*)d_in[0];
    const float* zim  = (const float*)d_in[1];
    const float* ctl  = (const float*)d_in[2];
    const float* mem0 = (const float*)d_in[3];
    const float* ptr0 = (const float*)d_in[4];
    const float* Wqr  = (const float*)d_in[5];
    const float* Wqi  = (const float*)d_in[6];
    const float* Wkr  = (const float*)d_in[7];
    const float* Wki  = (const float*)d_in[8];
    const float* Wvr  = (const float*)d_in[9];
    const float* Wvi  = (const float*)d_in[10];
    float* out = (float*)d_out;

    // zero the active_slots accumulator (last output element) before atomics
    hipMemsetAsync((char*)d_out + ((size_t)out_size - 1) * sizeof(float), 0,
                   sizeof(float), stream);

    crsn_fused<<<NBATCH, 256, 0, stream>>>(zre, zim, ctl, mem0, ptr0,
                                           Wqr, Wqi, Wkr, Wki, Wvr, Wvi, out);
}